// Round 6
// baseline (307.270 us; speedup 1.0000x reference)
//
#include <hip/hip_runtime.h>
#include <hip/hip_bf16.h>
#include <cstdint>
#include <cstddef>

#define BB 2
#define SS 2048
#define EE 1024
#define HH 16
#define MM (BB*SS)   // 4096

typedef __bf16 bf16;
typedef __bf16 bf16x8 __attribute__((ext_vector_type(8)));
typedef float f32x4 __attribute__((ext_vector_type(4)));

#define GLD16(gsrc, ldst) \
  __builtin_amdgcn_global_load_lds((const __attribute__((address_space(1))) void*)(gsrc), \
                                   (__attribute__((address_space(3))) void*)(ldst), 16, 0, 0)

// ---------------- f32 -> bf16 convert ----------------
__global__ __launch_bounds__(256) void cvt_f32_bf16(const float* __restrict__ src,
                                                    bf16* __restrict__ dst, int n) {
    int i = (blockIdx.x * 256 + threadIdx.x) * 8;
    if (i >= n) return;
    float4 a = *(const float4*)(src + i);
    float4 b = *(const float4*)(src + i + 4);
    bf16 o[8] = {(bf16)a.x,(bf16)a.y,(bf16)a.z,(bf16)a.w,
                 (bf16)b.x,(bf16)b.y,(bf16)b.z,(bf16)b.w};
    *(uint4*)(dst + i) = *(uint4*)o;
}

// convert the 4 weight matrices (each 1M elems) in one launch
__global__ __launch_bounds__(256) void cvt4(const float* __restrict__ a, const float* __restrict__ b,
                                            const float* __restrict__ c, const float* __restrict__ d,
                                            bf16* __restrict__ oa, bf16* __restrict__ ob,
                                            bf16* __restrict__ oc, bf16* __restrict__ od) {
    int sel = blockIdx.y;
    const float* s = sel == 0 ? a : sel == 1 ? b : sel == 2 ? c : d;
    bf16* o       = sel == 0 ? oa : sel == 1 ? ob : sel == 2 ? oc : od;
    int i = (blockIdx.x * 256 + threadIdx.x) * 8;
    float4 x = *(const float4*)(s + i);
    float4 y = *(const float4*)(s + i + 4);
    bf16 t[8] = {(bf16)x.x,(bf16)x.y,(bf16)x.z,(bf16)x.w,
                 (bf16)y.x,(bf16)y.y,(bf16)y.z,(bf16)y.w};
    *(uint4*)(o + i) = *(uint4*)t;
}

// ---------------- 128x128 GEMM, global_load_lds staging ----------------
template<int MODE>
__global__ __launch_bounds__(256) void gemm128(const bf16* __restrict__ A,
                                               const bf16* __restrict__ W0,
                                               const bf16* __restrict__ W1,
                                               const bf16* __restrict__ W2,
                                               const float* __restrict__ b0,
                                               const float* __restrict__ b1,
                                               const float* __restrict__ b2,
                                               void* __restrict__ o0,
                                               void* __restrict__ o1,
                                               void* __restrict__ o2) {
    __shared__ bf16 Al[128*64];
    __shared__ bf16 Bl[128*64];
    const int t = threadIdx.x;
    const int wsel = blockIdx.x >> 3;
    const int n0 = (blockIdx.x & 7) * 128;
    const int m0 = blockIdx.y * 128;
    const bf16* W  = wsel == 0 ? W0 : wsel == 1 ? W1 : W2;
    const float* bias = wsel == 0 ? b0 : wsel == 1 ? b1 : b2;
    void* outp = wsel == 0 ? o0 : wsel == 1 ? o1 : o2;

    const int w = t >> 6, lane = t & 63, lg = lane >> 4, li = lane & 15;
    const int wr = w >> 1, wc = w & 1;
    f32x4 acc[4][4] = {};

    for (int k0 = 0; k0 < 1024; k0 += 64) {
        __syncthreads();
        #pragma unroll
        for (int i = 0; i < 4; ++i) {
            int f = i * 256 + t;            // 0..1023
            int row = f >> 3, c = (f & 7) * 8;
            GLD16(A + (size_t)(m0 + row) * 1024 + k0 + c, Al + f * 8);
            GLD16(W + (size_t)(n0 + row) * 1024 + k0 + c, Bl + f * 8);
        }
        __syncthreads();
        #pragma unroll
        for (int ks = 0; ks < 2; ++ks) {
            bf16x8 af[4], bf_[4];
            #pragma unroll
            for (int m = 0; m < 4; ++m)
                af[m] = *(const bf16x8*)&Al[(wr*64 + m*16 + li)*64 + ks*32 + lg*8];
            #pragma unroll
            for (int n = 0; n < 4; ++n)
                bf_[n] = *(const bf16x8*)&Bl[(wc*64 + n*16 + li)*64 + ks*32 + lg*8];
            #pragma unroll
            for (int m = 0; m < 4; ++m)
                #pragma unroll
                for (int n = 0; n < 4; ++n)
                    acc[m][n] = __builtin_amdgcn_mfma_f32_16x16x32_bf16(af[m], bf_[n], acc[m][n], 0,0,0);
        }
    }
    #pragma unroll
    for (int m = 0; m < 4; ++m)
      #pragma unroll
      for (int n = 0; n < 4; ++n)
        #pragma unroll
        for (int r = 0; r < 4; ++r) {
            int row = m0 + wr*64 + m*16 + lg*4 + r;
            int col = n0 + wc*64 + n*16 + li;
            float v = acc[m][n][r] + bias[col];
            if (MODE == 0) {
                int b = row >> 11, s = row & (SS-1);
                int h = col >> 6, d = col & 63;
                ((bf16*)outp)[(((size_t)(b*HH + h)*SS + s) << 6) + d] = (bf16)v;
            } else {
                ((float*)outp)[(size_t)row*1024 + col] = v;
            }
        }
}

// ---------------- V transpose: [B*H][S][64] -> [B*H][64][S] ----------------
__global__ __launch_bounds__(256) void transpose_v(const bf16* __restrict__ V,
                                                   bf16* __restrict__ Vt) {
    __shared__ bf16 L[64][72];
    const int bh = blockIdx.y, s0 = blockIdx.x * 64, t = threadIdx.x;
    for (int id = t; id < 512; id += 256) {
        int row = id >> 3, c = id & 7;
        *(uint4*)&L[row][c*8] = *(const uint4*)&V[((size_t)bh*SS + s0 + row)*64 + c*8];
    }
    __syncthreads();
    for (int id = t; id < 512; id += 256) {
        int d = id >> 3, c = id & 7;
        bf16 tmp[8];
        #pragma unroll
        for (int jj = 0; jj < 8; ++jj) tmp[jj] = L[c*8 + jj][d];
        *(uint4*)&Vt[((size_t)bh*64 + d)*SS + s0 + c*8] = *(uint4*)tmp;
    }
}

// ---------------- ALiBi attention: in-register P, 32x32 wave sub-tiles -----
// wave w: jh = w&1 (j-half of 64-tile), qh = w>>1 (q-half).
// QK swapped: sc[jt][cbq] = mfma(K_rows, Q) -> lane owns q=cbq*16+li, j=jt*16+lg*4+r.
// That D-layout IS the PV A-fragment under k-permutation k=lg*8+jt*4+r, so P
// goes f32 -> exp2 -> bf16 pack -> PV mfma entirely in registers (no LDS P).
// V B-fragment under the same permutation = two b64 reads of staged Vt tile.
// O partials (jh pair) reduced once per block through reused LDS.
__global__ __launch_bounds__(256) void attn_kernel(const bf16* __restrict__ Q,
                                                   const bf16* __restrict__ Kk,
                                                   const bf16* __restrict__ Vt,
                                                   float* __restrict__ wout,
                                                   bf16* __restrict__ aout) {
    __shared__ bf16 Ks[2][64*64];   // 16 KB (reused as Obuf[2][64][64] at end)
    __shared__ bf16 Vs[2][64*64];   // 16 KB
    __shared__ float Lred[2][64];

    // XCD-cluster swizzle: 128 consecutive new-linear blocks per XCD slot ->
    // all 32 q-tiles of a head land on one XCD (K/V 512KB stays L2-resident).
    const int lin = blockIdx.x + (int)(gridDim.x * blockIdx.y);
    const int nl  = (lin & 7) * 128 + (lin >> 3);
    const int qt = nl & 31, bh = nl >> 5;

    const int b = bh >> 4, h = bh & 15;
    const int q0 = qt * 64;
    const int t = threadIdx.x, w = t >> 6, lane = t & 63, lg = lane >> 4, li = lane & 15;
    const int jh = w & 1, qh = w >> 1;
    const float slope = exp2f(-(float)(h + 1));
    const size_t kvbase = (size_t)bh * SS * 64;
    const size_t vtbase = (size_t)bh * 64 * SS;
    const float L2E = 1.4426950408889634f;
    const float K1 = 0.125f * L2E;
    const float C  = slope * L2E;
    const float C64 = C * 64.f;

    // Q fragments: B-operand, rows q = q0 + qh*32 + cbq*16 + li
    bf16x8 aq[2][2];
    #pragma unroll
    for (int cbq = 0; cbq < 2; ++cbq) {
        const bf16* qptr = Q + kvbase + (size_t)(q0 + qh*32 + cbq*16 + li) * 64;
        aq[cbq][0] = *(const bf16x8*)(qptr + lg*8);
        aq[cbq][1] = *(const bf16x8*)(qptr + 32 + lg*8);
    }

    const int swz = (li & 7) << 4;

    // ---- pass A: row sums l (K staged, dbuf, 1 barrier/iter) ----
    float cj[2][4];
    #pragma unroll
    for (int jt = 0; jt < 2; ++jt)
        #pragma unroll
        for (int r = 0; r < 4; ++r)
            cj[jt][r] = C * (float)(jh*32 + jt*16 + lg*4 + r - (SS-1));
    float lp[2] = {0.f, 0.f};

    #pragma unroll
    for (int i = 0; i < 2; ++i) {
        int f = i*256 + t; int row = f >> 3, c16 = f & 7;
        GLD16(Kk + kvbase + (size_t)row*64 + (c16 ^ (row & 7))*8, &Ks[0][0] + f*8);
    }
    __syncthreads();
    for (int kt = 0; kt < 32; ++kt) {
        const int cur = kt & 1;
        if (kt + 1 < 32) {
            #pragma unroll
            for (int i = 0; i < 2; ++i) {
                int f = i*256 + t; int row = f >> 3, c16 = f & 7;
                GLD16(Kk + kvbase + (size_t)((kt+1)*64 + row)*64 + (c16 ^ (row & 7))*8,
                      &Ks[cur^1][0] + f*8);
            }
        }
        const char* Ksb = (const char*)&Ks[cur][0];
        bf16x8 ak[2][2];
        #pragma unroll
        for (int jt = 0; jt < 2; ++jt) {
            int row = jh*32 + jt*16 + li;
            ak[jt][0] = *(const bf16x8*)(Ksb + row*128 + ((     lg*16) ^ swz));
            ak[jt][1] = *(const bf16x8*)(Ksb + row*128 + ((64 + lg*16) ^ swz));
        }
        f32x4 sc[2][2] = {};
        __builtin_amdgcn_s_setprio(1);
        #pragma unroll
        for (int jt = 0; jt < 2; ++jt)
            #pragma unroll
            for (int cbq = 0; cbq < 2; ++cbq) {
                sc[jt][cbq] = __builtin_amdgcn_mfma_f32_16x16x32_bf16(ak[jt][0], aq[cbq][0], sc[jt][cbq], 0,0,0);
                sc[jt][cbq] = __builtin_amdgcn_mfma_f32_16x16x32_bf16(ak[jt][1], aq[cbq][1], sc[jt][cbq], 0,0,0);
            }
        __builtin_amdgcn_s_setprio(0);
        #pragma unroll
        for (int jt = 0; jt < 2; ++jt) {
            #pragma unroll
            for (int cbq = 0; cbq < 2; ++cbq)
                #pragma unroll
                for (int r = 0; r < 4; ++r)
                    lp[cbq] += __builtin_amdgcn_exp2f(fmaf(sc[jt][cbq][r], K1, cj[jt][r]));
            #pragma unroll
            for (int r = 0; r < 4; ++r) cj[jt][r] += C64;
        }
        __syncthreads();
    }
    #pragma unroll
    for (int cbq = 0; cbq < 2; ++cbq) {
        lp[cbq] += __shfl_xor(lp[cbq], 16);
        lp[cbq] += __shfl_xor(lp[cbq], 32);
    }
    if (lg == 0) {
        Lred[jh][qh*32 + li]      = lp[0];
        Lred[jh][qh*32 + 16 + li] = lp[1];
    }
    // issue pass-B tile-0 staging before the barrier (overlaps Lred publish)
    #pragma unroll
    for (int i = 0; i < 2; ++i) {
        int f = i*256 + t; int row = f >> 3, c16 = f & 7;
        GLD16(Kk + kvbase + (size_t)row*64 + (c16 ^ (row & 7))*8, &Ks[0][0] + f*8);
        GLD16(Vt + vtbase + (size_t)row*SS + (c16 ^ (row & 7))*8, &Vs[0][0] + f*8);
    }
    __syncthreads();
    float lgl[2];
    #pragma unroll
    for (int cbq = 0; cbq < 2; ++cbq) {
        int qi = qh*32 + cbq*16 + li;
        lgl[cbq] = __builtin_amdgcn_logf(Lred[0][qi] + Lred[1][qi]);
    }
    // prefolded exponent constants: C*(j-2047) - log2(l)
    float ecr[2][2][4];
    #pragma unroll
    for (int jt = 0; jt < 2; ++jt)
        #pragma unroll
        for (int cbq = 0; cbq < 2; ++cbq)
            #pragma unroll
            for (int r = 0; r < 4; ++r)
                ecr[jt][cbq][r] = C * (float)(jh*32 + jt*16 + lg*4 + r - (SS-1)) - lgl[cbq];

    // ---- pass B: weights write + in-register PV ----
    f32x4 acc[2][4] = {};
    float* wrow0 = wout + ((size_t)bh*SS + q0 + qh*32 +      li) * SS;
    float* wrow1 = wout + ((size_t)bh*SS + q0 + qh*32 + 16 + li) * SS;

    for (int kt = 0; kt < 32; ++kt) {
        const int cur = kt & 1;
        const int j0 = kt * 64;
        if (kt + 1 < 32) {
            #pragma unroll
            for (int i = 0; i < 2; ++i) {
                int f = i*256 + t; int row = f >> 3, c16 = f & 7;
                GLD16(Kk + kvbase + (size_t)(j0 + 64 + row)*64 + (c16 ^ (row & 7))*8,
                      &Ks[cur^1][0] + f*8);
                GLD16(Vt + vtbase + (size_t)row*SS + j0 + 64 + (c16 ^ (row & 7))*8,
                      &Vs[cur^1][0] + f*8);
            }
        }
        const char* Ksb = (const char*)&Ks[cur][0];
        const char* Vsb = (const char*)&Vs[cur][0];
        bf16x8 ak[2][2];
        #pragma unroll
        for (int jt = 0; jt < 2; ++jt) {
            int row = jh*32 + jt*16 + li;
            ak[jt][0] = *(const bf16x8*)(Ksb + row*128 + ((     lg*16) ^ swz));
            ak[jt][1] = *(const bf16x8*)(Ksb + row*128 + ((64 + lg*16) ^ swz));
        }
        f32x4 sc[2][2] = {};
        __builtin_amdgcn_s_setprio(1);
        #pragma unroll
        for (int jt = 0; jt < 2; ++jt)
            #pragma unroll
            for (int cbq = 0; cbq < 2; ++cbq) {
                sc[jt][cbq] = __builtin_amdgcn_mfma_f32_16x16x32_bf16(ak[jt][0], aq[cbq][0], sc[jt][cbq], 0,0,0);
                sc[jt][cbq] = __builtin_amdgcn_mfma_f32_16x16x32_bf16(ak[jt][1], aq[cbq][1], sc[jt][cbq], 0,0,0);
            }
        __builtin_amdgcn_s_setprio(0);
        // exp2 -> normalized weights (f32 store) + bf16 P pack (in register)
        float4 wv[2][2];
        #pragma unroll
        for (int jt = 0; jt < 2; ++jt)
            #pragma unroll
            for (int cbq = 0; cbq < 2; ++cbq) {
                float4 v;
                v.x = __builtin_amdgcn_exp2f(fmaf(sc[jt][cbq][0], K1, ecr[jt][cbq][0]));
                v.y = __builtin_amdgcn_exp2f(fmaf(sc[jt][cbq][1], K1, ecr[jt][cbq][1]));
                v.z = __builtin_amdgcn_exp2f(fmaf(sc[jt][cbq][2], K1, ecr[jt][cbq][2]));
                v.w = __builtin_amdgcn_exp2f(fmaf(sc[jt][cbq][3], K1, ecr[jt][cbq][3]));
                wv[jt][cbq] = v;
                float* wr = (cbq == 0 ? wrow0 : wrow1);
                *(float4*)&wr[j0 + jh*32 + jt*16 + lg*4] = v;
                ecr[jt][cbq][0] += C64; ecr[jt][cbq][1] += C64;
                ecr[jt][cbq][2] += C64; ecr[jt][cbq][3] += C64;
            }
        bf16x8 pa[2];
        #pragma unroll
        for (int cbq = 0; cbq < 2; ++cbq) {
            bf16x8 p;
            p[0] = (bf16)wv[0][cbq].x; p[1] = (bf16)wv[0][cbq].y;
            p[2] = (bf16)wv[0][cbq].z; p[3] = (bf16)wv[0][cbq].w;
            p[4] = (bf16)wv[1][cbq].x; p[5] = (bf16)wv[1][cbq].y;
            p[6] = (bf16)wv[1][cbq].z; p[7] = (bf16)wv[1][cbq].w;
            pa[cbq] = p;
        }
        // V B-fragments under the same k-permutation: two b64 per d0-tile
        bf16x8 vb[4];
        #pragma unroll
        for (int d0 = 0; d0 < 4; ++d0) {
            int row = d0*16 + li;
            uint2 u0 = *(const uint2*)(Vsb + row*128 + ((jh*64      + lg*8) ^ swz));
            uint2 u1 = *(const uint2*)(Vsb + row*128 + ((jh*64 + 32 + lg*8) ^ swz));
            uint4 uu = {u0.x, u0.y, u1.x, u1.y};
            vb[d0] = __builtin_bit_cast(bf16x8, uu);
        }
        __builtin_amdgcn_s_setprio(1);
        #pragma unroll
        for (int cbq = 0; cbq < 2; ++cbq)
            #pragma unroll
            for (int d0 = 0; d0 < 4; ++d0)
                acc[cbq][d0] = __builtin_amdgcn_mfma_f32_16x16x32_bf16(pa[cbq], vb[d0], acc[cbq][d0], 0,0,0);
        __builtin_amdgcn_s_setprio(0);
        __syncthreads();
    }

    // ---- O reduction across jh wave-pairs (reuse Ks as Obuf[2][64][64]) ----
    bf16* Obuf = &Ks[0][0];
    #pragma unroll
    for (int cbq = 0; cbq < 2; ++cbq)
        #pragma unroll
        for (int d0 = 0; d0 < 4; ++d0)
            #pragma unroll
            for (int r = 0; r < 4; ++r)
                Obuf[jh*4096 + (qh*32 + cbq*16 + lg*4 + r)*64 + d0*16 + li] =
                    (bf16)acc[cbq][d0][r];
    __syncthreads();
    {
        int q = t >> 2, dc = (t & 3) << 4;
        const bf16* o0 = Obuf +        q*64 + dc;
        const bf16* o1 = Obuf + 4096 + q*64 + dc;
        bf16x8 a0 = *(const bf16x8*)(o0),     a1 = *(const bf16x8*)(o0 + 8);
        bf16x8 b0 = *(const bf16x8*)(o1),     b1 = *(const bf16x8*)(o1 + 8);
        bf16 ov[16];
        #pragma unroll
        for (int e = 0; e < 8; ++e) {
            ov[e]     = (bf16)((float)a0[e] + (float)b0[e]);
            ov[8 + e] = (bf16)((float)a1[e] + (float)b1[e]);
        }
        bf16* dst = aout + ((size_t)(b*SS + q0 + q))*EE + h*64 + dc;
        *(uint4*)(dst)     = *(uint4*)(ov);
        *(uint4*)(dst + 8) = *(uint4*)(ov + 8);
    }
}

// ---------------- launcher ----------------
extern "C" void kernel_launch(void* const* d_in, const int* in_sizes, int n_in,
                              void* d_out, int out_size, void* d_ws, size_t ws_size,
                              hipStream_t stream) {
    const float* x   = (const float*)d_in[0];
    const float* Wq  = (const float*)d_in[1];
    const float* bq  = (const float*)d_in[2];
    const float* Wk  = (const float*)d_in[3];
    const float* bk  = (const float*)d_in[4];
    const float* Wv  = (const float*)d_in[5];
    const float* bv  = (const float*)d_in[6];
    const float* Wfc = (const float*)d_in[7];
    const float* bfc = (const float*)d_in[8];

    char* ws = (char*)d_ws;
    const size_t MB = 1024u*1024u;
    bf16* xb  = (bf16*)(ws + 0);        // 8 MB
    bf16* wqb = (bf16*)(ws + 8*MB);     // 2 MB
    bf16* wkb = (bf16*)(ws + 10*MB);
    bf16* wvb = (bf16*)(ws + 12*MB);
    bf16* wfb = (bf16*)(ws + 14*MB);
    bf16* Qb  = (bf16*)(ws + 16*MB);    // 8 MB  [B*H][S][64]
    bf16* Kb  = (bf16*)(ws + 24*MB);    // 8 MB
    bf16* Vb  = (bf16*)(ws + 32*MB);    // 8 MB
    bf16* Vtb = (bf16*)(ws + 40*MB);    // 8 MB  [B*H][64][S]
    bf16* Ab  = (bf16*)(ws + 48*MB);    // 8 MB  [B][S][E]

    float* outp = (float*)d_out;
    float* wout = outp + (size_t)BB*SS*EE;

    cvt_f32_bf16<<<dim3(4194304/8/256), 256, 0, stream>>>(x, xb, 4194304);
    cvt4<<<dim3(512, 4), 256, 0, stream>>>(Wq, Wk, Wv, Wfc, wqb, wkb, wvb, wfb);

    gemm128<0><<<dim3(24, 32), 256, 0, stream>>>(xb, wqb, wkb, wvb, bq, bk, bv, Qb, Kb, Vb);

    transpose_v<<<dim3(SS/64, BB*HH), 256, 0, stream>>>(Vb, Vtb);

    attn_kernel<<<dim3(32, 32), 256, 0, stream>>>(Qb, Kb, Vtb, wout, Ab);

    gemm128<1><<<dim3(8, 32), 256, 0, stream>>>(Ab, wfb, wfb, wfb, bfc, bfc, bfc, d_out, d_out, d_out);
}

// Round 8
// 299.774 us; speedup vs baseline: 1.0250x; 1.0250x over previous
//
#include <hip/hip_runtime.h>
#include <hip/hip_bf16.h>
#include <cstdint>
#include <cstddef>

#define BB 2
#define SS 2048
#define EE 1024
#define HH 16
#define MM (BB*SS)   // 4096

typedef __bf16 bf16;
typedef __bf16 bf16x8 __attribute__((ext_vector_type(8)));
typedef float f32x4 __attribute__((ext_vector_type(4)));

#define GLD16(gsrc, ldst) \
  __builtin_amdgcn_global_load_lds((const __attribute__((address_space(1))) void*)(gsrc), \
                                   (__attribute__((address_space(3))) void*)(ldst), 16, 0, 0)

#define VMWAIT(N) do { asm volatile("s_waitcnt vmcnt(" #N ")" ::: "memory"); \
                       __builtin_amdgcn_sched_barrier(0); } while (0)
#define XBAR() do { __builtin_amdgcn_s_barrier(); \
                    __builtin_amdgcn_sched_barrier(0); } while (0)

// ---------------- f32 -> bf16 convert ----------------
__global__ __launch_bounds__(256) void cvt_f32_bf16(const float* __restrict__ src,
                                                    bf16* __restrict__ dst, int n) {
    int i = (blockIdx.x * 256 + threadIdx.x) * 8;
    if (i >= n) return;
    float4 a = *(const float4*)(src + i);
    float4 b = *(const float4*)(src + i + 4);
    bf16 o[8] = {(bf16)a.x,(bf16)a.y,(bf16)a.z,(bf16)a.w,
                 (bf16)b.x,(bf16)b.y,(bf16)b.z,(bf16)b.w};
    *(uint4*)(dst + i) = *(uint4*)o;
}

// convert the 4 weight matrices (each 1M elems) in one launch
__global__ __launch_bounds__(256) void cvt4(const float* __restrict__ a, const float* __restrict__ b,
                                            const float* __restrict__ c, const float* __restrict__ d,
                                            bf16* __restrict__ oa, bf16* __restrict__ ob,
                                            bf16* __restrict__ oc, bf16* __restrict__ od) {
    int sel = blockIdx.y;
    const float* s = sel == 0 ? a : sel == 1 ? b : sel == 2 ? c : d;
    bf16* o       = sel == 0 ? oa : sel == 1 ? ob : sel == 2 ? oc : od;
    int i = (blockIdx.x * 256 + threadIdx.x) * 8;
    float4 x = *(const float4*)(s + i);
    float4 y = *(const float4*)(s + i + 4);
    bf16 t[8] = {(bf16)x.x,(bf16)x.y,(bf16)x.z,(bf16)x.w,
                 (bf16)y.x,(bf16)y.y,(bf16)y.z,(bf16)y.w};
    *(uint4*)(o + i) = *(uint4*)t;
}

// ---------------- 128x128 GEMM, global_load_lds staging ----------------
template<int MODE>
__global__ __launch_bounds__(256) void gemm128(const bf16* __restrict__ A,
                                               const bf16* __restrict__ W0,
                                               const bf16* __restrict__ W1,
                                               const bf16* __restrict__ W2,
                                               const float* __restrict__ b0,
                                               const float* __restrict__ b1,
                                               const float* __restrict__ b2,
                                               void* __restrict__ o0,
                                               void* __restrict__ o1,
                                               void* __restrict__ o2) {
    __shared__ bf16 Al[128*64];
    __shared__ bf16 Bl[128*64];
    const int t = threadIdx.x;
    const int wsel = blockIdx.x >> 3;
    const int n0 = (blockIdx.x & 7) * 128;
    const int m0 = blockIdx.y * 128;
    const bf16* W  = wsel == 0 ? W0 : wsel == 1 ? W1 : W2;
    const float* bias = wsel == 0 ? b0 : wsel == 1 ? b1 : b2;
    void* outp = wsel == 0 ? o0 : wsel == 1 ? o1 : o2;

    const int w = t >> 6, lane = t & 63, lg = lane >> 4, li = lane & 15;
    const int wr = w >> 1, wc = w & 1;
    f32x4 acc[4][4] = {};

    for (int k0 = 0; k0 < 1024; k0 += 64) {
        __syncthreads();
        #pragma unroll
        for (int i = 0; i < 4; ++i) {
            int f = i * 256 + t;            // 0..1023
            int row = f >> 3, c = (f & 7) * 8;
            GLD16(A + (size_t)(m0 + row) * 1024 + k0 + c, Al + f * 8);
            GLD16(W + (size_t)(n0 + row) * 1024 + k0 + c, Bl + f * 8);
        }
        __syncthreads();
        #pragma unroll
        for (int ks = 0; ks < 2; ++ks) {
            bf16x8 af[4], bf_[4];
            #pragma unroll
            for (int m = 0; m < 4; ++m)
                af[m] = *(const bf16x8*)&Al[(wr*64 + m*16 + li)*64 + ks*32 + lg*8];
            #pragma unroll
            for (int n = 0; n < 4; ++n)
                bf_[n] = *(const bf16x8*)&Bl[(wc*64 + n*16 + li)*64 + ks*32 + lg*8];
            #pragma unroll
            for (int m = 0; m < 4; ++m)
                #pragma unroll
                for (int n = 0; n < 4; ++n)
                    acc[m][n] = __builtin_amdgcn_mfma_f32_16x16x32_bf16(af[m], bf_[n], acc[m][n], 0,0,0);
        }
    }
    #pragma unroll
    for (int m = 0; m < 4; ++m)
      #pragma unroll
      for (int n = 0; n < 4; ++n)
        #pragma unroll
        for (int r = 0; r < 4; ++r) {
            int row = m0 + wr*64 + m*16 + lg*4 + r;
            int col = n0 + wc*64 + n*16 + li;
            float v = acc[m][n][r] + bias[col];
            if (MODE == 0) {
                int b = row >> 11, s = row & (SS-1);
                int h = col >> 6, d = col & 63;
                ((bf16*)outp)[(((size_t)(b*HH + h)*SS + s) << 6) + d] = (bf16)v;
            } else {
                ((float*)outp)[(size_t)row*1024 + col] = v;
            }
        }
}

// ---------------- V transpose: [B*H][S][64] -> [B*H][64][S] ----------------
__global__ __launch_bounds__(256) void transpose_v(const bf16* __restrict__ V,
                                                   bf16* __restrict__ Vt) {
    __shared__ bf16 L[64][72];
    const int bh = blockIdx.y, s0 = blockIdx.x * 64, t = threadIdx.x;
    for (int id = t; id < 512; id += 256) {
        int row = id >> 3, c = id & 7;
        *(uint4*)&L[row][c*8] = *(const uint4*)&V[((size_t)bh*SS + s0 + row)*64 + c*8];
    }
    __syncthreads();
    for (int id = t; id < 512; id += 256) {
        int d = id >> 3, c = id & 7;
        bf16 tmp[8];
        #pragma unroll
        for (int jj = 0; jj < 8; ++jj) tmp[jj] = L[c*8 + jj][d];
        *(uint4*)&Vt[((size_t)bh*64 + d)*SS + s0 + c*8] = *(uint4*)tmp;
    }
}

// ---------------- ALiBi attention: counted-vmcnt pipelined two-pass --------
// Same math/layout as validated R6 (in-register P, swapped QK, analytic max).
// Manual s_waitcnt vmcnt(N) + raw s_barrier (T4): K/V prefetch guaranteed
// landed, weight stores left in flight across barriers. Pass A: ring-4 K
// buffer, depth-2 prefetch, vmcnt(2). Pass B: dbuf K/V, vmcnt(4) leaves the
// 4 nontemporal weight stores outstanding.
__global__ __launch_bounds__(256) void attn_kernel(const bf16* __restrict__ Q,
                                                   const bf16* __restrict__ Kk,
                                                   const bf16* __restrict__ Vt,
                                                   float* __restrict__ wout,
                                                   bf16* __restrict__ aout) {
    __shared__ bf16 ring[4][64*64];   // 32 KB: A = K ring4; B = K2(0,1)+V2(2,3); epi = Obuf(0,1)
    __shared__ float Lred[2][64];

    // XCD-cluster swizzle: 128 consecutive new-linear blocks per XCD slot.
    const int lin = blockIdx.x + (int)(gridDim.x * blockIdx.y);
    const int nl  = (lin & 7) * 128 + (lin >> 3);
    const int qt = nl & 31, bh = nl >> 5;

    const int b = bh >> 4, h = bh & 15;
    const int q0 = qt * 64;
    const int t = threadIdx.x, w = t >> 6, lane = t & 63, lg = lane >> 4, li = lane & 15;
    const int jh = w & 1, qh = w >> 1;
    const float slope = exp2f(-(float)(h + 1));
    const size_t kvbase = (size_t)bh * SS * 64;
    const size_t vtbase = (size_t)bh * 64 * SS;
    const float L2E = 1.4426950408889634f;
    const float K1 = 0.125f * L2E;
    const float C  = slope * L2E;
    const float C64 = C * 64.f;

    // Q fragments: B-operand, rows q = q0 + qh*32 + cbq*16 + li
    bf16x8 aq[2][2];
    #pragma unroll
    for (int cbq = 0; cbq < 2; ++cbq) {
        const bf16* qptr = Q + kvbase + (size_t)(q0 + qh*32 + cbq*16 + li) * 64;
        aq[cbq][0] = *(const bf16x8*)(qptr + lg*8);
        aq[cbq][1] = *(const bf16x8*)(qptr + 32 + lg*8);
    }

    const int swz = (li & 7) << 4;

    // stage helpers: 2 GLD16/thread per 64x64 tile, inverse-swizzled source
    #define STAGE_K(J0, DST) do {                                              \
        _Pragma("unroll")                                                      \
        for (int i_ = 0; i_ < 2; ++i_) {                                       \
            int f_ = i_*256 + t; int row_ = f_ >> 3, c_ = f_ & 7;              \
            GLD16(Kk + kvbase + (size_t)((J0) + row_)*64 + (c_ ^ (row_ & 7))*8,\
                  (DST) + f_*8);                                               \
        } } while (0)
    #define STAGE_V(J0, DST) do {                                              \
        _Pragma("unroll")                                                      \
        for (int i_ = 0; i_ < 2; ++i_) {                                       \
            int f_ = i_*256 + t; int row_ = f_ >> 3, c_ = f_ & 7;              \
            GLD16(Vt + vtbase + (size_t)row_*SS + (J0) + (c_ ^ (row_ & 7))*8,  \
                  (DST) + f_*8);                                               \
        } } while (0)

    // ---- pass A: row sums l (K ring-4, depth-2 prefetch, counted vmcnt) ----
    float cj[2][4];
    #pragma unroll
    for (int jt = 0; jt < 2; ++jt)
        #pragma unroll
        for (int r = 0; r < 4; ++r)
            cj[jt][r] = C * (float)(jh*32 + jt*16 + lg*4 + r - (SS-1));
    float lp[2] = {0.f, 0.f};

    STAGE_K(0,  &ring[0][0]);
    STAGE_K(64, &ring[1][0]);
    VMWAIT(2);          // tile0 landed, tile1 in flight
    XBAR();
    for (int kt = 0; kt < 32; ++kt) {
        if (kt + 2 < 32) STAGE_K((kt+2)*64, &ring[(kt+2) & 3][0]);
        const char* Ksb = (const char*)&ring[kt & 3][0];
        bf16x8 ak[2][2];
        #pragma unroll
        for (int jt = 0; jt < 2; ++jt) {
            int row = jh*32 + jt*16 + li;
            ak[jt][0] = *(const bf16x8*)(Ksb + row*128 + ((     lg*16) ^ swz));
            ak[jt][1] = *(const bf16x8*)(Ksb + row*128 + ((64 + lg*16) ^ swz));
        }
        f32x4 sc[2][2] = {};
        __builtin_amdgcn_s_setprio(1);
        #pragma unroll
        for (int jt = 0; jt < 2; ++jt)
            #pragma unroll
            for (int cbq = 0; cbq < 2; ++cbq) {
                sc[jt][cbq] = __builtin_amdgcn_mfma_f32_16x16x32_bf16(ak[jt][0], aq[cbq][0], sc[jt][cbq], 0,0,0);
                sc[jt][cbq] = __builtin_amdgcn_mfma_f32_16x16x32_bf16(ak[jt][1], aq[cbq][1], sc[jt][cbq], 0,0,0);
            }
        __builtin_amdgcn_s_setprio(0);
        #pragma unroll
        for (int jt = 0; jt < 2; ++jt) {
            #pragma unroll
            for (int cbq = 0; cbq < 2; ++cbq)
                #pragma unroll
                for (int r = 0; r < 4; ++r)
                    lp[cbq] += __builtin_amdgcn_exp2f(fmaf(sc[jt][cbq][r], K1, cj[jt][r]));
            #pragma unroll
            for (int r = 0; r < 4; ++r) cj[jt][r] += C64;
        }
        if (kt < 30) { VMWAIT(2); } else { VMWAIT(0); }   // kt+1 tile guaranteed landed
        XBAR();
    }
    #pragma unroll
    for (int cbq = 0; cbq < 2; ++cbq) {
        lp[cbq] += __shfl_xor(lp[cbq], 16);
        lp[cbq] += __shfl_xor(lp[cbq], 32);
    }
    if (lg == 0) {
        Lred[jh][qh*32 + li]      = lp[0];
        Lred[jh][qh*32 + 16 + li] = lp[1];
    }
    // pass-B tile 0 staging overlaps the Lred publish
    STAGE_K(0, &ring[0][0]);
    STAGE_V(0, &ring[2][0]);
    asm volatile("s_waitcnt vmcnt(0) lgkmcnt(0)" ::: "memory");
    __builtin_amdgcn_sched_barrier(0);
    XBAR();
    float lgl[2];
    #pragma unroll
    for (int cbq = 0; cbq < 2; ++cbq) {
        int qi = qh*32 + cbq*16 + li;
        lgl[cbq] = __builtin_amdgcn_logf(Lred[0][qi] + Lred[1][qi]);
    }
    float ecr[2][2][4];
    #pragma unroll
    for (int jt = 0; jt < 2; ++jt)
        #pragma unroll
        for (int cbq = 0; cbq < 2; ++cbq)
            #pragma unroll
            for (int r = 0; r < 4; ++r)
                ecr[jt][cbq][r] = C * (float)(jh*32 + jt*16 + lg*4 + r - (SS-1)) - lgl[cbq];

    // ---- pass B: dbuf K/V; weights (nontemporal f32) + in-register PV ----
    f32x4 acc[2][4] = {};
    float* wrow0 = wout + ((size_t)bh*SS + q0 + qh*32 +      li) * SS;
    float* wrow1 = wout + ((size_t)bh*SS + q0 + qh*32 + 16 + li) * SS;

    for (int kt = 0; kt < 32; ++kt) {
        const int cur = kt & 1;
        const int j0 = kt * 64;
        if (kt + 1 < 32) {
            STAGE_K(j0 + 64, &ring[cur ^ 1][0]);
            STAGE_V(j0 + 64, &ring[2 + (cur ^ 1)][0]);
        }
        const char* Ksb = (const char*)&ring[cur][0];
        const char* Vsb = (const char*)&ring[2 + cur][0];
        bf16x8 ak[2][2];
        #pragma unroll
        for (int jt = 0; jt < 2; ++jt) {
            int row = jh*32 + jt*16 + li;
            ak[jt][0] = *(const bf16x8*)(Ksb + row*128 + ((     lg*16) ^ swz));
            ak[jt][1] = *(const bf16x8*)(Ksb + row*128 + ((64 + lg*16) ^ swz));
        }
        f32x4 sc[2][2] = {};
        __builtin_amdgcn_s_setprio(1);
        #pragma unroll
        for (int jt = 0; jt < 2; ++jt)
            #pragma unroll
            for (int cbq = 0; cbq < 2; ++cbq) {
                sc[jt][cbq] = __builtin_amdgcn_mfma_f32_16x16x32_bf16(ak[jt][0], aq[cbq][0], sc[jt][cbq], 0,0,0);
                sc[jt][cbq] = __builtin_amdgcn_mfma_f32_16x16x32_bf16(ak[jt][1], aq[cbq][1], sc[jt][cbq], 0,0,0);
            }
        __builtin_amdgcn_s_setprio(0);
        f32x4 wv[2][2];
        #pragma unroll
        for (int jt = 0; jt < 2; ++jt)
            #pragma unroll
            for (int cbq = 0; cbq < 2; ++cbq) {
                f32x4 v;
                v[0] = __builtin_amdgcn_exp2f(fmaf(sc[jt][cbq][0], K1, ecr[jt][cbq][0]));
                v[1] = __builtin_amdgcn_exp2f(fmaf(sc[jt][cbq][1], K1, ecr[jt][cbq][1]));
                v[2] = __builtin_amdgcn_exp2f(fmaf(sc[jt][cbq][2], K1, ecr[jt][cbq][2]));
                v[3] = __builtin_amdgcn_exp2f(fmaf(sc[jt][cbq][3], K1, ecr[jt][cbq][3]));
                wv[jt][cbq] = v;
                float* wr = (cbq == 0 ? wrow0 : wrow1);
                __builtin_nontemporal_store(v, (f32x4*)&wr[j0 + jh*32 + jt*16 + lg*4]);
                ecr[jt][cbq][0] += C64; ecr[jt][cbq][1] += C64;
                ecr[jt][cbq][2] += C64; ecr[jt][cbq][3] += C64;
            }
        bf16x8 pa[2];
        #pragma unroll
        for (int cbq = 0; cbq < 2; ++cbq) {
            bf16x8 p;
            p[0] = (bf16)wv[0][cbq][0]; p[1] = (bf16)wv[0][cbq][1];
            p[2] = (bf16)wv[0][cbq][2]; p[3] = (bf16)wv[0][cbq][3];
            p[4] = (bf16)wv[1][cbq][0]; p[5] = (bf16)wv[1][cbq][1];
            p[6] = (bf16)wv[1][cbq][2]; p[7] = (bf16)wv[1][cbq][3];
            pa[cbq] = p;
        }
        bf16x8 vb[4];
        #pragma unroll
        for (int d0 = 0; d0 < 4; ++d0) {
            int row = d0*16 + li;
            uint2 u0 = *(const uint2*)(Vsb + row*128 + ((jh*64      + lg*8) ^ swz));
            uint2 u1 = *(const uint2*)(Vsb + row*128 + ((jh*64 + 32 + lg*8) ^ swz));
            uint4 uu = {u0.x, u0.y, u1.x, u1.y};
            vb[d0] = __builtin_bit_cast(bf16x8, uu);
        }
        __builtin_amdgcn_s_setprio(1);
        #pragma unroll
        for (int cbq = 0; cbq < 2; ++cbq)
            #pragma unroll
            for (int d0 = 0; d0 < 4; ++d0)
                acc[cbq][d0] = __builtin_amdgcn_mfma_f32_16x16x32_bf16(pa[cbq], vb[d0], acc[cbq][d0], 0,0,0);
        __builtin_amdgcn_s_setprio(0);
        VMWAIT(4);   // K/V for kt+1 landed; this iter's 4 weight stores stay in flight
        XBAR();
    }

    // ---- O reduction across jh wave-pairs (reuse ring[0..1] as Obuf) ----
    bf16* Obuf = &ring[0][0];
    #pragma unroll
    for (int cbq = 0; cbq < 2; ++cbq)
        #pragma unroll
        for (int d0 = 0; d0 < 4; ++d0)
            #pragma unroll
            for (int r = 0; r < 4; ++r)
                Obuf[jh*4096 + (qh*32 + cbq*16 + lg*4 + r)*64 + d0*16 + li] =
                    (bf16)acc[cbq][d0][r];
    __syncthreads();
    {
        int q = t >> 2, dc = (t & 3) << 4;
        const bf16* o0 = Obuf +        q*64 + dc;
        const bf16* o1 = Obuf + 4096 + q*64 + dc;
        bf16x8 a0 = *(const bf16x8*)(o0),     a1 = *(const bf16x8*)(o0 + 8);
        bf16x8 b0 = *(const bf16x8*)(o1),     b1 = *(const bf16x8*)(o1 + 8);
        bf16 ov[16];
        #pragma unroll
        for (int e = 0; e < 8; ++e) {
            ov[e]     = (bf16)((float)a0[e] + (float)b0[e]);
            ov[8 + e] = (bf16)((float)a1[e] + (float)b1[e]);
        }
        bf16* dst = aout + ((size_t)(b*SS + q0 + q))*EE + h*64 + dc;
        *(uint4*)(dst)     = *(uint4*)(ov);
        *(uint4*)(dst + 8) = *(uint4*)(ov + 8);
    }
    #undef STAGE_K
    #undef STAGE_V
}

// ---------------- launcher ----------------
extern "C" void kernel_launch(void* const* d_in, const int* in_sizes, int n_in,
                              void* d_out, int out_size, void* d_ws, size_t ws_size,
                              hipStream_t stream) {
    const float* x   = (const float*)d_in[0];
    const float* Wq  = (const float*)d_in[1];
    const float* bq  = (const float*)d_in[2];
    const float* Wk  = (const float*)d_in[3];
    const float* bk  = (const float*)d_in[4];
    const float* Wv  = (const float*)d_in[5];
    const float* bv  = (const float*)d_in[6];
    const float* Wfc = (const float*)d_in[7];
    const float* bfc = (const float*)d_in[8];

    char* ws = (char*)d_ws;
    const size_t MB = 1024u*1024u;
    bf16* xb  = (bf16*)(ws + 0);        // 8 MB
    bf16* wqb = (bf16*)(ws + 8*MB);     // 2 MB
    bf16* wkb = (bf16*)(ws + 10*MB);
    bf16* wvb = (bf16*)(ws + 12*MB);
    bf16* wfb = (bf16*)(ws + 14*MB);
    bf16* Qb  = (bf16*)(ws + 16*MB);    // 8 MB  [B*H][S][64]
    bf16* Kb  = (bf16*)(ws + 24*MB);    // 8 MB
    bf16* Vb  = (bf16*)(ws + 32*MB);    // 8 MB
    bf16* Vtb = (bf16*)(ws + 40*MB);    // 8 MB  [B*H][64][S]
    bf16* Ab  = (bf16*)(ws + 48*MB);    // 8 MB  [B][S][E]

    float* outp = (float*)d_out;
    float* wout = outp + (size_t)BB*SS*EE;

    cvt_f32_bf16<<<dim3(4194304/8/256), 256, 0, stream>>>(x, xb, 4194304);
    cvt4<<<dim3(512, 4), 256, 0, stream>>>(Wq, Wk, Wv, Wfc, wqb, wkb, wvb, wfb);

    gemm128<0><<<dim3(24, 32), 256, 0, stream>>>(xb, wqb, wkb, wvb, bq, bk, bv, Qb, Kb, Vb);

    transpose_v<<<dim3(SS/64, BB*HH), 256, 0, stream>>>(Vb, Vtb);

    attn_kernel<<<dim3(32, 32), 256, 0, stream>>>(Qb, Kb, Vtb, wout, Ab);

    gemm128<1><<<dim3(8, 32), 256, 0, stream>>>(Ab, wfb, wfb, wfb, bfc, bfc, bfc, d_out, d_out, d_out);
}